// Round 1
// baseline (3605.352 us; speedup 1.0000x reference)
//
#include <hip/hip_runtime.h>
#include <stdint.h>

// ============================================================================
// ScannedMultiLayerLSTM: T=64, B=32, W=1024, L=4
// Persistent pipelined kernel:
//   - 256 blocks (1/CU), block -> (layer, 16 hidden units)
//   - 4 waves/block split K=2048 (Wx||Wh) into 4x512, LDS reduce
//   - B-fragments (weights) preloaded into VGPRs once (64 frags = 256 VGPRs/wave)
//   - cross-block sync via device-scope flag atomics (wavefront pipeline, no grid barrier)
//   - dtype hedges: x/weights bf16-vs-fp32 detected on device; resets int32/byte/float
// ============================================================================

typedef unsigned short u16;
typedef unsigned int u32;
typedef __attribute__((ext_vector_type(8))) short short8;
typedef __attribute__((ext_vector_type(4))) float f32x4;

#define NT 64
#define NB 32
#define NW 1024
#define NLAY 4
#define G4 4096

// workspace layout (bytes)
#define HIST_OFF 0                 // bf16 hist[L][65][B][W] : slot t = h entering step t
#define CST_OFF 17039360           // fp32 c_state[L][B][W]
#define FLAGS_OFF 17563648         // int flags[L][T]  (256)
#define RMASK_OFF 17564672         // int rmask[T][B]  (2048)
#define MODE_OFF 17572864          // int modes[2]: [0]=bf16? [1]=resets mode (0=byte,1=int32,2=float)

__device__ __forceinline__ float bf2f(u16 u) {
  union { u32 i; float f; } v; v.i = ((u32)u) << 16; return v.f;
}
__device__ __forceinline__ u16 f2bf(float f) {
  union { float f; u32 i; } v; v.f = f;
  u32 b = v.i;
  return (u16)((b + 0x7FFFu + ((b >> 16) & 1u)) >> 16);
}
__device__ __forceinline__ float sigmoidf_(float x) { return 1.f / (1.f + __expf(-x)); }
__device__ __forceinline__ float tanhfast(float x) {
  float cx = fminf(fmaxf(x, -15.f), 15.f);
  float e = __expf(2.f * cx);
  return (e - 1.f) / (e + 1.f);
}

// ---------------------------------------------------------------------------
// setup: detect dtypes, normalize resets, zero flags. 1 block x 256 threads.
// ---------------------------------------------------------------------------
__global__ void lstm_setup(const void* __restrict__ x, const void* __restrict__ resets,
                           int* __restrict__ modes, int* __restrict__ rmask,
                           int* __restrict__ flags) {
  __shared__ int votes_bf16, bad_int, bad_float;
  __shared__ int sm_rmode;
  int tid = threadIdx.x;
  if (tid == 0) { votes_bf16 = 0; bad_int = 0; bad_float = 0; }
  __syncthreads();

  // x dtype: if bf16 pairs, low-16 of each u32 word is a bf16 whose exponent
  // (bits 14..7) clusters near 126; if fp32, those are uniform mantissa bits.
  {
    u32 w = ((const u32*)x)[tid];            // 1 KB, safe either way
    int e = (int)((w >> 7) & 0xFFu);
    if (e >= 100 && e <= 140) atomicAdd(&votes_bf16, 1);
  }
  // resets storage: first 128 words (512B, safe for byte mode too)
  if (tid < 128) {
    u32 r = ((const u32*)resets)[tid];
    if (r > 1u) atomicAdd(&bad_int, 1);
    if (r != 0u && r != 0x3F800000u) atomicAdd(&bad_float, 1);
  }
  __syncthreads();
  if (tid == 0) {
    int mbf = (votes_bf16 >= 192) ? 1 : 0;
    int rmode;
    if (bad_int == 0) rmode = 1;            // int32 0/1
    else if (bad_float == 0) rmode = 2;     // float 0.0/1.0
    else rmode = 0;                         // bytes
    modes[0] = mbf;
    modes[1] = rmode;
    sm_rmode = rmode;
  }
  __syncthreads();
  int rmode = sm_rmode;
#pragma unroll
  for (int k = 0; k < 8; ++k) {
    int idx = tid * 8 + k;                  // 0..2047
    int val;
    if (rmode == 1) val = (((const int*)resets)[idx] != 0);
    else if (rmode == 2) val = (((const u32*)resets)[idx] != 0u);
    else val = (((const unsigned char*)resets)[idx] != 0);
    rmask[idx] = val;
  }
  flags[tid] = 0;                           // exactly 256 flags
}

// ---------------------------------------------------------------------------
// prep: copy h0 -> hist slot0 (bf16), c0 -> c_state (fp32). 512 blocks x 256.
// ---------------------------------------------------------------------------
template <bool BF16>
__global__ void lstm_prep(const void* __restrict__ c0, const void* __restrict__ h0,
                          const int* __restrict__ modes,
                          u16* __restrict__ hist, float* __restrict__ cst) {
  if ((modes[0] != 0) != BF16) return;
  int idx = blockIdx.x * 256 + threadIdx.x; // 0..131071 over [L][B][W]
  int l = idx >> 15;
  int rem = idx & 32767;
  float cv, hv;
  if (BF16) {
    cv = bf2f(((const u16*)c0)[idx]);
    hv = bf2f(((const u16*)h0)[idx]);
  } else {
    cv = ((const float*)c0)[idx];
    hv = ((const float*)h0)[idx];
  }
  cst[idx] = cv;
  hist[(size_t)l * (65 * NB * NW) + rem] = f2bf(hv);
}

// ---------------------------------------------------------------------------
// main persistent kernel. 256 blocks x 256 threads (4 waves).
// ---------------------------------------------------------------------------
template <bool BF16>
__global__ __launch_bounds__(256, 1) void lstm_main(
    const void* __restrict__ xv, const void* __restrict__ Wxv,
    const void* __restrict__ Whv, const void* __restrict__ biasv,
    void* __restrict__ outv, const int* __restrict__ modes,
    const int* __restrict__ rmask, u16* __restrict__ hist,
    float* __restrict__ cst, int* __restrict__ flags) {
  if ((modes[0] != 0) != BF16) return;

  const int l = blockIdx.x >> 6;      // layer
  const int s = blockIdx.x & 63;      // hidden-slice
  const int hb = s * 16;
  const int tid = threadIdx.x;
  const int wave = tid >> 6;
  const int lane = tid & 63;
  const bool xpart = (wave < 2);      // waves 0,1: y@Wx half; waves 2,3: h@Wh half
  const int krel = (wave & 1) * 512;  // K offset within this half's 1024 rows
  const int lrow = lane & 15;
  const int lk8 = (lane >> 4) * 8;

  __shared__ float red[4][2][4][16][17]; // [wave][mtile][gate][row][col(+pad)]

  // ---- one-time weight preload: B-fragments B[k][n], n=lane&15, k=lk8+j ----
  short8 wfrag[4][16]; // [gate][ktile]  = 256 VGPRs
  {
    const size_t base = (size_t)l * NW * G4;
#pragma unroll
    for (int g = 0; g < 4; ++g) {
#pragma unroll
      for (int kt = 0; kt < 16; ++kt) {
        size_t off = base + (size_t)(krel + kt * 32 + lk8) * G4 + (size_t)(g * 1024 + hb + lrow);
        short8 v;
        if (BF16) {
          const u16* p = (xpart ? (const u16*)Wxv : (const u16*)Whv) + off;
#pragma unroll
          for (int j = 0; j < 8; ++j) v[j] = (short)p[(size_t)j * G4];
        } else {
          const float* p = (xpart ? (const float*)Wxv : (const float*)Whv) + off;
#pragma unroll
          for (int j = 0; j < 8; ++j) v[j] = (short)f2bf(p[(size_t)j * G4]);
        }
        wfrag[g][kt] = v;
      }
    }
  }

  short8 z8;
#pragma unroll
  for (int j = 0; j < 8; ++j) z8[j] = 0;

#pragma unroll 1
  for (int t = 0; t < NT; ++t) {
    // ---- wait for producers (device-scope acquire) ----
    if (tid == 0) {
      if (l > 0) {
        while (__hip_atomic_load(&flags[(l - 1) * NT + t], __ATOMIC_ACQUIRE,
                                 __HIP_MEMORY_SCOPE_AGENT) < 64)
          __builtin_amdgcn_s_sleep(2);
      }
      if (t > 0) {
        while (__hip_atomic_load(&flags[l * NT + (t - 1)], __ATOMIC_ACQUIRE,
                                 __HIP_MEMORY_SCOPE_AGENT) < 64)
          __builtin_amdgcn_s_sleep(2);
      }
    }
    __syncthreads();

    // ---- A sources ----
    const u16* srcH = hist + ((size_t)l * 65 + t) * (NB * NW);             // h[l][t-1]
    const u16* srcY = hist + ((size_t)(l - 1) * 65 + (t + 1)) * (NB * NW); // h[l-1][t]
    const u16* srcXb = (const u16*)xv + (size_t)t * NB * NW;
    const float* srcXf = (const float*)xv + (size_t)t * NB * NW;

    int rm0 = 0, rm1 = 0;
    if (!xpart) {
      rm0 = rmask[t * NB + lrow];
      rm1 = rmask[t * NB + 16 + lrow];
    }

    f32x4 acc[2][4];
    f32x4 zf = {0.f, 0.f, 0.f, 0.f};
#pragma unroll
    for (int mt = 0; mt < 2; ++mt)
#pragma unroll
      for (int g = 0; g < 4; ++g) acc[mt][g] = zf;

#pragma unroll
    for (int half = 0; half < 2; ++half) {
      short8 af[8][2];
#pragma unroll
      for (int q = 0; q < 8; ++q) {
        int kk = krel + (half * 8 + q) * 32 + lk8;
        short8 a0, a1;
        if (!xpart) {
          a0 = *(const short8*)(srcH + (size_t)lrow * NW + kk);
          a1 = *(const short8*)(srcH + (size_t)(lrow + 16) * NW + kk);
          if (rm0) a0 = z8;
          if (rm1) a1 = z8;
        } else if (l > 0) {
          a0 = *(const short8*)(srcY + (size_t)lrow * NW + kk);
          a1 = *(const short8*)(srcY + (size_t)(lrow + 16) * NW + kk);
        } else if (BF16) {
          a0 = *(const short8*)(srcXb + (size_t)lrow * NW + kk);
          a1 = *(const short8*)(srcXb + (size_t)(lrow + 16) * NW + kk);
        } else {
          const f32x4* p0 = (const f32x4*)(srcXf + (size_t)lrow * NW + kk);
          const f32x4* p1 = (const f32x4*)(srcXf + (size_t)(lrow + 16) * NW + kk);
          f32x4 x0a = p0[0], x0b = p0[1], x1a = p1[0], x1b = p1[1];
#pragma unroll
          for (int j = 0; j < 4; ++j) {
            a0[j] = (short)f2bf(x0a[j]);
            a0[j + 4] = (short)f2bf(x0b[j]);
            a1[j] = (short)f2bf(x1a[j]);
            a1[j + 4] = (short)f2bf(x1b[j]);
          }
        }
        af[q][0] = a0;
        af[q][1] = a1;
      }
#pragma unroll
      for (int q = 0; q < 8; ++q) {
        int kt = half * 8 + q;
#pragma unroll
        for (int g = 0; g < 4; ++g) {
          acc[0][g] = __builtin_amdgcn_mfma_f32_16x16x32_bf16(af[q][0], wfrag[g][kt], acc[0][g], 0, 0, 0);
          acc[1][g] = __builtin_amdgcn_mfma_f32_16x16x32_bf16(af[q][1], wfrag[g][kt], acc[1][g], 0, 0, 0);
        }
      }
    }

    // ---- cross-wave reduce via LDS ----
#pragma unroll
    for (int mt = 0; mt < 2; ++mt)
#pragma unroll
      for (int g = 0; g < 4; ++g)
#pragma unroll
        for (int r = 0; r < 4; ++r)
          red[wave][mt][g][(lane >> 4) * 4 + r][lrow] = acc[mt][g][r];
    __syncthreads();

    // ---- epilogue: each thread finishes 2 (b,n) cells ----
#pragma unroll
    for (int hh = 0; hh < 2; ++hh) {
      int o = tid + hh * 256;
      int b = o >> 4, n = o & 15;
      int mt = b >> 4, r = b & 15;
      float gv[4];
#pragma unroll
      for (int g = 0; g < 4; ++g) {
        float acc4 = red[0][mt][g][r][n] + red[1][mt][g][r][n] +
                     red[2][mt][g][r][n] + red[3][mt][g][r][n];
        int bidx = l * G4 + g * 1024 + hb + n;
        float bias = BF16 ? bf2f(((const u16*)biasv)[bidx]) : ((const float*)biasv)[bidx];
        gv[g] = acc4 + bias;
      }
      int cidx = (l * NB + b) * NW + hb + n;
      float c_old = cst[cidx];
      if (rmask[t * NB + b]) c_old = 0.f;
      float ci = sigmoidf_(gv[0]);
      float cf = sigmoidf_(gv[1]);
      float cg = tanhfast(gv[2]);
      float co = sigmoidf_(gv[3]);
      float cn = cf * c_old + ci * cg;
      float hn = co * tanhfast(cn);
      cst[cidx] = cn;
      hist[((size_t)l * 65 + (t + 1)) * (NB * NW) + (size_t)b * NW + hb + n] = f2bf(hn);
      if (l == NLAY - 1) {
        size_t oy = ((size_t)t * NB + b) * NW + hb + n;
        if (BF16) ((u16*)outv)[oy] = f2bf(hn);
        else ((float*)outv)[oy] = hn;
      }
      if (t == NT - 1) {
        size_t oc = (size_t)NT * NB * NW + ((size_t)l * NB + b) * NW + hb + n;
        size_t oh = oc + (size_t)NLAY * NB * NW;
        if (BF16) {
          ((u16*)outv)[oc] = f2bf(cn);
          ((u16*)outv)[oh] = f2bf(hn);
        } else {
          ((float*)outv)[oc] = cn;
          ((float*)outv)[oh] = hn;
        }
      }
    }

    // ---- publish h[l][t] ----
    __threadfence();
    __syncthreads();
    if (tid == 0)
      __hip_atomic_fetch_add(&flags[l * NT + t], 1, __ATOMIC_RELEASE,
                             __HIP_MEMORY_SCOPE_AGENT);
  }
}

// ---------------------------------------------------------------------------
extern "C" void kernel_launch(void* const* d_in, const int* in_sizes, int n_in,
                              void* d_out, int out_size, void* d_ws, size_t ws_size,
                              hipStream_t stream) {
  const void* x = d_in[0];
  const void* resets = d_in[1];
  const void* c0 = d_in[2];
  const void* h0 = d_in[3];
  const void* Wx = d_in[4];
  const void* Wh = d_in[5];
  const void* bias = d_in[6];

  char* ws = (char*)d_ws;
  u16* hist = (u16*)(ws + HIST_OFF);
  float* cst = (float*)(ws + CST_OFF);
  int* flags = (int*)(ws + FLAGS_OFF);
  int* rmask = (int*)(ws + RMASK_OFF);
  int* modes = (int*)(ws + MODE_OFF);

  lstm_setup<<<1, 256, 0, stream>>>(x, resets, modes, rmask, flags);
  lstm_prep<true><<<512, 256, 0, stream>>>(c0, h0, modes, hist, cst);
  lstm_prep<false><<<512, 256, 0, stream>>>(c0, h0, modes, hist, cst);
  lstm_main<true><<<256, 256, 0, stream>>>(x, Wx, Wh, bias, d_out, modes, rmask, hist, cst, flags);
  lstm_main<false><<<256, 256, 0, stream>>>(x, Wx, Wh, bias, d_out, modes, rmask, hist, cst, flags);
}

// Round 2
// 1286.298 us; speedup vs baseline: 2.8029x; 2.8029x over previous
//
#include <hip/hip_runtime.h>
#include <stdint.h>

// ============================================================================
// ScannedMultiLayerLSTM: T=64, B=32, W=1024, L=4
// Round 2: fence-free pipelined persistent kernel.
//   - 256 blocks (1/CU), block -> (layer, 16 hidden units)
//   - 4 waves/block split K=2048 (Wx||Wh) into 4x512, LDS reduce
//   - weights preloaded into regs once (256 VGPR/AGPR per lane)
//   - sync: per-block flag SLOTS written/read with relaxed agent atomics
//     (write-through sc stores; NO __threadfence -> no buffer_wbl2,
//      NO acquire loads -> no buffer_inv, NO contended atomicAdd)
//   - h published as packed u32 write-through atomic stores
//   - c-state lives in registers (block-private)
// ============================================================================

typedef unsigned short u16;
typedef unsigned int u32;
typedef __attribute__((ext_vector_type(8))) short short8;
typedef __attribute__((ext_vector_type(4))) float f32x4;

#define NT 64
#define NB 32
#define NW 1024
#define NLAY 4
#define G4 4096

// workspace layout (bytes)
#define HIST_OFF 0                 // bf16 hist[L][65][B][W] : slot t = h entering step t
#define FLAGS_OFF 17039360         // int flags[L][T][64] (65536 B)
#define RMASK_OFF 17104896         // int rmask[T][B] (8192 B)
#define MODE_OFF 17113088          // int modes[2]

__device__ __forceinline__ float bf2f(u16 u) {
  union { u32 i; float f; } v; v.i = ((u32)u) << 16; return v.f;
}
__device__ __forceinline__ u16 f2bf(float f) {
  union { float f; u32 i; } v; v.f = f;
  u32 b = v.i;
  return (u16)((b + 0x7FFFu + ((b >> 16) & 1u)) >> 16);
}
__device__ __forceinline__ float sigmoidf_(float x) { return 1.f / (1.f + __expf(-x)); }
__device__ __forceinline__ float tanhfast(float x) {
  float cx = fminf(fmaxf(x, -15.f), 15.f);
  float e = __expf(2.f * cx);
  return (e - 1.f) / (e + 1.f);
}

// ---------------------------------------------------------------------------
// setup: detect dtypes, normalize resets, zero flag slots. 1 block x 256.
// ---------------------------------------------------------------------------
__global__ void lstm_setup(const void* __restrict__ x, const void* __restrict__ resets,
                           int* __restrict__ modes, int* __restrict__ rmask,
                           int* __restrict__ flags) {
  __shared__ int votes_bf16, bad_int, bad_float;
  __shared__ int sm_rmode;
  int tid = threadIdx.x;
  if (tid == 0) { votes_bf16 = 0; bad_int = 0; bad_float = 0; }
  __syncthreads();

  {
    u32 w = ((const u32*)x)[tid];            // 1 KB, safe either way
    int e = (int)((w >> 7) & 0xFFu);
    if (e >= 100 && e <= 140) atomicAdd(&votes_bf16, 1);
  }
  if (tid < 128) {
    u32 r = ((const u32*)resets)[tid];
    if (r > 1u) atomicAdd(&bad_int, 1);
    if (r != 0u && r != 0x3F800000u) atomicAdd(&bad_float, 1);
  }
  __syncthreads();
  if (tid == 0) {
    int mbf = (votes_bf16 >= 192) ? 1 : 0;
    int rmode;
    if (bad_int == 0) rmode = 1;
    else if (bad_float == 0) rmode = 2;
    else rmode = 0;
    modes[0] = mbf;
    modes[1] = rmode;
    sm_rmode = rmode;
  }
  __syncthreads();
  int rmode = sm_rmode;
#pragma unroll
  for (int k = 0; k < 8; ++k) {
    int idx = tid * 8 + k;                  // 0..2047
    int val;
    if (rmode == 1) val = (((const int*)resets)[idx] != 0);
    else if (rmode == 2) val = (((const u32*)resets)[idx] != 0u);
    else val = (((const unsigned char*)resets)[idx] != 0);
    rmask[idx] = val;
  }
  for (int k = tid; k < NLAY * NT * 64; k += 256) flags[k] = 0;
}

// ---------------------------------------------------------------------------
// prep: copy h0 -> hist slot0 (bf16). 512 blocks x 256.
// ---------------------------------------------------------------------------
template <bool BF16>
__global__ void lstm_prep(const void* __restrict__ h0, const int* __restrict__ modes,
                          u16* __restrict__ hist) {
  if ((modes[0] != 0) != BF16) return;
  int idx = blockIdx.x * 256 + threadIdx.x; // 0..131071 over [L][B][W]
  int l = idx >> 15;
  int rem = idx & 32767;
  float hv;
  if (BF16) hv = bf2f(((const u16*)h0)[idx]);
  else      hv = ((const float*)h0)[idx];
  hist[(size_t)l * (65 * NB * NW) + rem] = f2bf(hv);
}

// ---------------------------------------------------------------------------
// main persistent kernel. 256 blocks x 256 threads (4 waves).
// ---------------------------------------------------------------------------
template <bool BF16>
__global__ __launch_bounds__(256, 1) void lstm_main(
    const void* __restrict__ xv, const void* __restrict__ Wxv,
    const void* __restrict__ Whv, const void* __restrict__ biasv,
    const void* __restrict__ c0v,
    void* __restrict__ outv, const int* __restrict__ modes,
    const int* __restrict__ rmask, u16* __restrict__ hist,
    int* __restrict__ flags) {
  if ((modes[0] != 0) != BF16) return;

  const int l = blockIdx.x >> 6;      // layer
  const int s = blockIdx.x & 63;      // hidden-slice
  const int hb = s * 16;
  const int tid = threadIdx.x;
  const int wave = tid >> 6;
  const int lane = tid & 63;
  const bool xpart = (wave < 2);      // waves 0,1: y@Wx half; waves 2,3: h@Wh half
  const int krel = (wave & 1) * 512;  // K offset within this half's 1024 rows
  const int lrow = lane & 15;
  const int lk8 = (lane >> 4) * 8;

  // epilogue mapping: thread -> 2 adjacent n for one b
  const int eb = tid >> 3;            // 0..31  (batch row)
  const int n0 = (tid & 7) * 2;       // 0,2,..,14
  const int emt = eb >> 4, er = eb & 15;

  __shared__ float red[4][2][4][16][17]; // [wave][mtile][gate][row][col(+pad)]

  // ---- one-time weight preload: B-fragments B[k][n], n=lane&15, k=lk8+j ----
  short8 wfrag[4][16]; // [gate][ktile]
  {
    const size_t base = (size_t)l * NW * G4;
#pragma unroll
    for (int g = 0; g < 4; ++g) {
#pragma unroll
      for (int kt = 0; kt < 16; ++kt) {
        size_t off = base + (size_t)(krel + kt * 32 + lk8) * G4 + (size_t)(g * 1024 + hb + lrow);
        short8 v;
        if (BF16) {
          const u16* p = (xpart ? (const u16*)Wxv : (const u16*)Whv) + off;
#pragma unroll
          for (int j = 0; j < 8; ++j) v[j] = (short)p[(size_t)j * G4];
        } else {
          const float* p = (xpart ? (const float*)Wxv : (const float*)Whv) + off;
#pragma unroll
          for (int j = 0; j < 8; ++j) v[j] = (short)f2bf(p[(size_t)j * G4]);
        }
        wfrag[g][kt] = v;
      }
    }
  }

  // ---- bias preload for this thread's 2 cells ----
  float bias_r[4][2];
#pragma unroll
  for (int g = 0; g < 4; ++g)
#pragma unroll
    for (int j = 0; j < 2; ++j) {
      int bidx = l * G4 + g * 1024 + hb + n0 + j;
      bias_r[g][j] = BF16 ? bf2f(((const u16*)biasv)[bidx]) : ((const float*)biasv)[bidx];
    }

  float creg[2] = {0.f, 0.f};

  short8 z8;
#pragma unroll
  for (int j = 0; j < 8; ++j) z8[j] = 0;

#pragma unroll 1
  for (int t = 0; t < NT; ++t) {
    // ---- wait for producers: per-slot relaxed polls, no fences ----
    if (wave == 0 && l > 0) {
      const int* p = &flags[((l - 1) * NT + t) * 64 + lane];
      while (__hip_atomic_load(p, __ATOMIC_RELAXED, __HIP_MEMORY_SCOPE_AGENT) == 0)
        __builtin_amdgcn_s_sleep(1);
    }
    if (wave == 1 && t > 0) {
      const int* p = &flags[(l * NT + (t - 1)) * 64 + lane];
      while (__hip_atomic_load(p, __ATOMIC_RELAXED, __HIP_MEMORY_SCOPE_AGENT) == 0)
        __builtin_amdgcn_s_sleep(1);
    }
    __syncthreads();

    // ---- A sources ----
    const u16* srcH = hist + ((size_t)l * 65 + t) * (NB * NW);             // h[l][t-1]
    const u16* srcY = hist + ((size_t)(l - 1) * 65 + (t + 1)) * (NB * NW); // h[l-1][t]
    const u16* srcXb = (const u16*)xv + (size_t)t * NB * NW;
    const float* srcXf = (const float*)xv + (size_t)t * NB * NW;

    int rm0 = 0, rm1 = 0;
    if (!xpart) {
      rm0 = rmask[t * NB + lrow];
      rm1 = rmask[t * NB + 16 + lrow];
    }

    f32x4 acc[2][4];
    f32x4 zf = {0.f, 0.f, 0.f, 0.f};
#pragma unroll
    for (int mt = 0; mt < 2; ++mt)
#pragma unroll
      for (int g = 0; g < 4; ++g) acc[mt][g] = zf;

#pragma unroll
    for (int half = 0; half < 2; ++half) {
      short8 af[8][2];
#pragma unroll
      for (int q = 0; q < 8; ++q) {
        int kk = krel + (half * 8 + q) * 32 + lk8;
        short8 a0, a1;
        if (!xpart) {
          a0 = *(const short8*)(srcH + (size_t)lrow * NW + kk);
          a1 = *(const short8*)(srcH + (size_t)(lrow + 16) * NW + kk);
          if (rm0) a0 = z8;
          if (rm1) a1 = z8;
        } else if (l > 0) {
          a0 = *(const short8*)(srcY + (size_t)lrow * NW + kk);
          a1 = *(const short8*)(srcY + (size_t)(lrow + 16) * NW + kk);
        } else if (BF16) {
          a0 = *(const short8*)(srcXb + (size_t)lrow * NW + kk);
          a1 = *(const short8*)(srcXb + (size_t)(lrow + 16) * NW + kk);
        } else {
          const f32x4* p0 = (const f32x4*)(srcXf + (size_t)lrow * NW + kk);
          const f32x4* p1 = (const f32x4*)(srcXf + (size_t)(lrow + 16) * NW + kk);
          f32x4 x0a = p0[0], x0b = p0[1], x1a = p1[0], x1b = p1[1];
#pragma unroll
          for (int j = 0; j < 4; ++j) {
            a0[j] = (short)f2bf(x0a[j]);
            a0[j + 4] = (short)f2bf(x0b[j]);
            a1[j] = (short)f2bf(x1a[j]);
            a1[j + 4] = (short)f2bf(x1b[j]);
          }
        }
        af[q][0] = a0;
        af[q][1] = a1;
      }
#pragma unroll
      for (int q = 0; q < 8; ++q) {
        int kt = half * 8 + q;
#pragma unroll
        for (int g = 0; g < 4; ++g) {
          acc[0][g] = __builtin_amdgcn_mfma_f32_16x16x32_bf16(af[q][0], wfrag[g][kt], acc[0][g], 0, 0, 0);
          acc[1][g] = __builtin_amdgcn_mfma_f32_16x16x32_bf16(af[q][1], wfrag[g][kt], acc[1][g], 0, 0, 0);
        }
      }
    }

    // ---- cross-wave reduce via LDS ----
#pragma unroll
    for (int mt = 0; mt < 2; ++mt)
#pragma unroll
      for (int g = 0; g < 4; ++g)
#pragma unroll
        for (int r = 0; r < 4; ++r)
          red[wave][mt][g][(lane >> 4) * 4 + r][lrow] = acc[mt][g][r];
    __syncthreads();

    // ---- epilogue: this thread's 2 cells (eb, n0) (eb, n0+1) ----
    {
      int rm = rmask[t * NB + eb];
      float hn[2];
#pragma unroll
      for (int j = 0; j < 2; ++j) {
        int n = n0 + j;
        float gv[4];
#pragma unroll
        for (int g = 0; g < 4; ++g)
          gv[g] = red[0][emt][g][er][n] + red[1][emt][g][er][n] +
                  red[2][emt][g][er][n] + red[3][emt][g][er][n] + bias_r[g][j];
        float c_old = creg[j];
        if (t == 0) {
          int cidx = (l * NB + eb) * NW + hb + n;
          c_old = BF16 ? bf2f(((const u16*)c0v)[cidx]) : ((const float*)c0v)[cidx];
        }
        if (rm) c_old = 0.f;
        float ci = sigmoidf_(gv[0]);
        float cf = sigmoidf_(gv[1]);
        float cg = tanhfast(gv[2]);
        float co = sigmoidf_(gv[3]);
        float cn = cf * c_old + ci * cg;
        hn[j] = co * tanhfast(cn);
        creg[j] = cn;
      }
      // publish h (write-through, packed 2x bf16)
      u32 hp = (u32)f2bf(hn[0]) | ((u32)f2bf(hn[1]) << 16);
      size_t hoff = ((size_t)l * 65 + (t + 1)) * (NB * NW) + (size_t)eb * NW + hb + n0;
      __hip_atomic_store((u32*)(hist + hoff), hp, __ATOMIC_RELAXED, __HIP_MEMORY_SCOPE_AGENT);
      // y output (layer 3)
      if (l == NLAY - 1) {
        size_t oy = ((size_t)t * NB + eb) * NW + hb + n0;
        if (BF16) ((u32*)outv)[oy >> 1] = hp;
        else { ((float*)outv)[oy] = hn[0]; ((float*)outv)[oy + 1] = hn[1]; }
      }
      // final c/h outputs
      if (t == NT - 1) {
        size_t oc = (size_t)NT * NB * NW + ((size_t)l * NB + eb) * NW + hb + n0;
        size_t oh = oc + (size_t)NLAY * NB * NW;
        if (BF16) {
          u32 cp = (u32)f2bf(creg[0]) | ((u32)f2bf(creg[1]) << 16);
          ((u32*)outv)[oc >> 1] = cp;
          ((u32*)outv)[oh >> 1] = hp;
        } else {
          ((float*)outv)[oc] = creg[0];
          ((float*)outv)[oc + 1] = creg[1];
          ((float*)outv)[oh] = hn[0];
          ((float*)outv)[oh + 1] = hn[1];
        }
      }
    }

    // ---- publish flag: drain this wave's stores, barrier, slot store ----
    asm volatile("s_waitcnt vmcnt(0)" ::: "memory");
    __syncthreads();
    if (tid == 0)
      __hip_atomic_store(&flags[(l * NT + t) * 64 + s], 1, __ATOMIC_RELAXED,
                         __HIP_MEMORY_SCOPE_AGENT);
  }
}

// ---------------------------------------------------------------------------
extern "C" void kernel_launch(void* const* d_in, const int* in_sizes, int n_in,
                              void* d_out, int out_size, void* d_ws, size_t ws_size,
                              hipStream_t stream) {
  const void* x = d_in[0];
  const void* resets = d_in[1];
  const void* c0 = d_in[2];
  const void* h0 = d_in[3];
  const void* Wx = d_in[4];
  const void* Wh = d_in[5];
  const void* bias = d_in[6];

  char* ws = (char*)d_ws;
  u16* hist = (u16*)(ws + HIST_OFF);
  int* flags = (int*)(ws + FLAGS_OFF);
  int* rmask = (int*)(ws + RMASK_OFF);
  int* modes = (int*)(ws + MODE_OFF);

  lstm_setup<<<1, 256, 0, stream>>>(x, resets, modes, rmask, flags);
  lstm_prep<true><<<512, 256, 0, stream>>>(h0, modes, hist);
  lstm_prep<false><<<512, 256, 0, stream>>>(h0, modes, hist);
  lstm_main<true><<<256, 256, 0, stream>>>(x, Wx, Wh, bias, c0, d_out, modes, rmask, hist, flags);
  lstm_main<false><<<256, 256, 0, stream>>>(x, Wx, Wh, bias, c0, d_out, modes, rmask, hist, flags);
}

// Round 3
// 1037.855 us; speedup vs baseline: 3.4739x; 1.2394x over previous
//
#include <hip/hip_runtime.h>
#include <stdint.h>

// ============================================================================
// ScannedMultiLayerLSTM: T=64, B=32, W=1024, L=4
// Round 3: sentinel-polling pipelined persistent kernel (no flags at all).
//   - 256 blocks (1/CU), block -> (layer, 16 hidden units)
//   - 4 waves/block split K=2048 (Wx||Wh) into 4x512, LDS reduce
//   - weights preloaded into regs once (256 VGPR/AGPR per lane)
//   - handoff: producers publish h via write-through u32 stores; consumers
//     poll the DATA with global_load_dwordx4 sc0 sc1 until != 0xAAAAAAAA
//     (hist slots 1..64 explicitly poisoned by a prep kernel)
//   - no __threadfence, no vmcnt drain, no flag round trips, no pre-barrier
// ============================================================================

typedef unsigned short u16;
typedef unsigned int u32;
typedef __attribute__((ext_vector_type(8))) short short8;
typedef __attribute__((ext_vector_type(4))) float f32x4;
typedef __attribute__((ext_vector_type(4))) unsigned int u32x4;

#define NT 64
#define NB 32
#define NW 1024
#define NLAY 4
#define G4 4096
#define POISON 0xAAAAAAAAu

// workspace layout (bytes)
#define HIST_OFF 0                 // bf16 hist[L][65][B][W] : slot t = h entering step t
#define RMASK_OFF 17104896         // int rmask[T][B] (8192 B)
#define MODE_OFF 17113088          // int modes[2]

__device__ __forceinline__ float bf2f(u16 u) {
  union { u32 i; float f; } v; v.i = ((u32)u) << 16; return v.f;
}
__device__ __forceinline__ u16 f2bf(float f) {
  union { float f; u32 i; } v; v.f = f;
  u32 b = v.i;
  return (u16)((b + 0x7FFFu + ((b >> 16) & 1u)) >> 16);
}
__device__ __forceinline__ float sigmoidf_(float x) { return 1.f / (1.f + __expf(-x)); }
__device__ __forceinline__ float tanhfast(float x) {
  float cx = fminf(fmaxf(x, -15.f), 15.f);
  float e = __expf(2.f * cx);
  return (e - 1.f) / (e + 1.f);
}
union CastU { u32x4 u; short8 s; };
__device__ __forceinline__ short8 as_s8(u32x4 v) { CastU c; c.u = v; return c.s; }
__device__ __forceinline__ u32x4 as_u4(short8 v) { CastU c; c.s = v; return c.u; }

// ---------------------------------------------------------------------------
// sentinel poll: load 16 chunks (2 rows x 8) cache-bypassed until all fresh.
// rowA/rowB point at (row, kbase) in hist; chunk q is +q*32 u16.
// ---------------------------------------------------------------------------
__device__ __forceinline__ void poll_half(const u16* rowA, const u16* rowB, u32x4 r[16]) {
  for (;;) {
#pragma unroll
    for (int q = 0; q < 8; ++q) {
      asm volatile("global_load_dwordx4 %0, %1, off sc0 sc1" : "=v"(r[q]) : "v"(rowA + q * 32));
      asm volatile("global_load_dwordx4 %0, %1, off sc0 sc1" : "=v"(r[8 + q]) : "v"(rowB + q * 32));
    }
    asm volatile("s_waitcnt vmcnt(0)"
                 : "+v"(r[0]), "+v"(r[1]), "+v"(r[2]), "+v"(r[3]), "+v"(r[4]), "+v"(r[5]),
                   "+v"(r[6]), "+v"(r[7]), "+v"(r[8]), "+v"(r[9]), "+v"(r[10]), "+v"(r[11]),
                   "+v"(r[12]), "+v"(r[13]), "+v"(r[14]), "+v"(r[15])
                 :
                 : "memory");
    bool ok = true;
    const u16* probe = rowA;
    bool have = false;
#pragma unroll
    for (int c = 0; c < 16; ++c) {
      bool f = (r[c].x != POISON) && (r[c].y != POISON) && (r[c].z != POISON) && (r[c].w != POISON);
      if (!f && !have) { probe = (c < 8) ? (rowA + c * 32) : (rowB + (c - 8) * 32); have = true; }
      ok &= f;
    }
    if (ok) return;
    // throttled single-chunk probe until the laggard lands, then full re-sweep
    for (;;) {
      __builtin_amdgcn_s_sleep(4);
      u32x4 v;
      asm volatile("global_load_dwordx4 %0, %1, off sc0 sc1" : "=v"(v) : "v"(probe));
      asm volatile("s_waitcnt vmcnt(0)" : "+v"(v) : : "memory");
      if ((v.x != POISON) && (v.y != POISON) && (v.z != POISON) && (v.w != POISON)) break;
    }
  }
}

// ---------------------------------------------------------------------------
// setup: detect dtypes, normalize resets. 1 block x 256 threads.
// ---------------------------------------------------------------------------
__global__ void lstm_setup(const void* __restrict__ x, const void* __restrict__ resets,
                           int* __restrict__ modes, int* __restrict__ rmask) {
  __shared__ int votes_bf16, bad_int, bad_float;
  __shared__ int sm_rmode;
  int tid = threadIdx.x;
  if (tid == 0) { votes_bf16 = 0; bad_int = 0; bad_float = 0; }
  __syncthreads();
  {
    u32 w = ((const u32*)x)[tid];
    int e = (int)((w >> 7) & 0xFFu);
    if (e >= 100 && e <= 140) atomicAdd(&votes_bf16, 1);
  }
  if (tid < 128) {
    u32 r = ((const u32*)resets)[tid];
    if (r > 1u) atomicAdd(&bad_int, 1);
    if (r != 0u && r != 0x3F800000u) atomicAdd(&bad_float, 1);
  }
  __syncthreads();
  if (tid == 0) {
    int mbf = (votes_bf16 >= 192) ? 1 : 0;
    int rmode;
    if (bad_int == 0) rmode = 1;
    else if (bad_float == 0) rmode = 2;
    else rmode = 0;
    modes[0] = mbf;
    modes[1] = rmode;
    sm_rmode = rmode;
  }
  __syncthreads();
  int rmode = sm_rmode;
#pragma unroll
  for (int k = 0; k < 8; ++k) {
    int idx = tid * 8 + k;
    int val;
    if (rmode == 1) val = (((const int*)resets)[idx] != 0);
    else if (rmode == 2) val = (((const u32*)resets)[idx] != 0u);
    else val = (((const unsigned char*)resets)[idx] != 0);
    rmask[idx] = val;
  }
}

// ---------------------------------------------------------------------------
// poison hist slots 1..64 of every layer to the sentinel. 4096 blocks x 256.
// ---------------------------------------------------------------------------
__global__ void lstm_poison(u32* __restrict__ hist32) {
  int g = (blockIdx.x * 256 + threadIdx.x) * 4; // u32 index, 4,194,304 total
  int l = g >> 20;                              // 1,048,576 u32 per layer
  int r = g & 1048575;
  u32x4 v = {POISON, POISON, POISON, POISON};
  *(u32x4*)(hist32 + ((size_t)l * 65 + 1) * 16384 + r) = v;
}

// ---------------------------------------------------------------------------
// prep: copy h0 -> hist slot0 (bf16). 512 blocks x 256.
// ---------------------------------------------------------------------------
template <bool BF16>
__global__ void lstm_prep(const void* __restrict__ h0, const int* __restrict__ modes,
                          u16* __restrict__ hist) {
  if ((modes[0] != 0) != BF16) return;
  int idx = blockIdx.x * 256 + threadIdx.x; // 0..131071 over [L][B][W]
  int l = idx >> 15;
  int rem = idx & 32767;
  float hv;
  if (BF16) hv = bf2f(((const u16*)h0)[idx]);
  else      hv = ((const float*)h0)[idx];
  hist[(size_t)l * (65 * NB * NW) + rem] = f2bf(hv);
}

// ---------------------------------------------------------------------------
// main persistent kernel. 256 blocks x 256 threads (4 waves).
// ---------------------------------------------------------------------------
template <bool BF16>
__global__ __launch_bounds__(256, 1) void lstm_main(
    const void* __restrict__ xv, const void* __restrict__ Wxv,
    const void* __restrict__ Whv, const void* __restrict__ biasv,
    const void* __restrict__ c0v,
    void* __restrict__ outv, const int* __restrict__ modes,
    const int* __restrict__ rmask, u16* __restrict__ hist) {
  if ((modes[0] != 0) != BF16) return;

  const int l = blockIdx.x >> 6;      // layer
  const int s = blockIdx.x & 63;      // hidden-slice
  const int hb = s * 16;
  const int tid = threadIdx.x;
  const int wave = tid >> 6;
  const int lane = tid & 63;
  const bool xpart = (wave < 2);      // waves 0,1: y@Wx half; waves 2,3: h@Wh half
  const int krel = (wave & 1) * 512;  // K offset within this half's 1024 rows
  const int lrow = lane & 15;
  const int lk8 = (lane >> 4) * 8;

  // epilogue mapping: thread -> 2 adjacent n for one b
  const int eb = tid >> 3;            // 0..31  (batch row)
  const int n0 = (tid & 7) * 2;       // 0,2,..,14
  const int emt = eb >> 4, er = eb & 15;

  __shared__ float red[4][2][4][16][17]; // [wave][mtile][gate][row][col(+pad)]

  // ---- one-time weight preload: B-fragments B[k][n], n=lane&15, k=lk8+j ----
  short8 wfrag[4][16]; // [gate][ktile]
  {
    const size_t base = (size_t)l * NW * G4;
#pragma unroll
    for (int g = 0; g < 4; ++g) {
#pragma unroll
      for (int kt = 0; kt < 16; ++kt) {
        size_t off = base + (size_t)(krel + kt * 32 + lk8) * G4 + (size_t)(g * 1024 + hb + lrow);
        short8 v;
        if (BF16) {
          const u16* p = (xpart ? (const u16*)Wxv : (const u16*)Whv) + off;
#pragma unroll
          for (int j = 0; j < 8; ++j) v[j] = (short)p[(size_t)j * G4];
        } else {
          const float* p = (xpart ? (const float*)Wxv : (const float*)Whv) + off;
#pragma unroll
          for (int j = 0; j < 8; ++j) v[j] = (short)f2bf(p[(size_t)j * G4]);
        }
        wfrag[g][kt] = v;
      }
    }
  }

  // ---- bias preload for this thread's 2 cells ----
  float bias_r[4][2];
#pragma unroll
  for (int g = 0; g < 4; ++g)
#pragma unroll
    for (int j = 0; j < 2; ++j) {
      int bidx = l * G4 + g * 1024 + hb + n0 + j;
      bias_r[g][j] = BF16 ? bf2f(((const u16*)biasv)[bidx]) : ((const float*)biasv)[bidx];
    }

  float creg[2] = {0.f, 0.f};

#pragma unroll 1
  for (int t = 0; t < NT; ++t) {
    const u16* srcH = hist + ((size_t)l * 65 + t) * (NB * NW);             // h[l][t-1]
    const u16* srcY = hist + ((size_t)(l - 1) * 65 + (t + 1)) * (NB * NW); // h[l-1][t]
    const u16* srcXb = (const u16*)xv + (size_t)t * NB * NW;
    const float* srcXf = (const float*)xv + (size_t)t * NB * NW;

    int rm0 = 0, rm1 = 0;
    if (!xpart) {
      rm0 = rmask[t * NB + lrow];
      rm1 = rmask[t * NB + 16 + lrow];
    }

    f32x4 acc[2][4];
    f32x4 zf = {0.f, 0.f, 0.f, 0.f};
#pragma unroll
    for (int mt = 0; mt < 2; ++mt)
#pragma unroll
      for (int g = 0; g < 4; ++g) acc[mt][g] = zf;

#pragma unroll
    for (int half = 0; half < 2; ++half) {
      u32x4 r[16];
      const int kbase = krel + half * 256 + lk8;
      if (xpart) {
        if (l > 0) {
          poll_half(srcY + (size_t)lrow * NW + kbase, srcY + (size_t)(lrow + 16) * NW + kbase, r);
        } else if (BF16) {
#pragma unroll
          for (int q = 0; q < 8; ++q) {
            r[q] = *(const u32x4*)(srcXb + (size_t)lrow * NW + kbase + q * 32);
            r[8 + q] = *(const u32x4*)(srcXb + (size_t)(lrow + 16) * NW + kbase + q * 32);
          }
        } else {
#pragma unroll
          for (int q = 0; q < 8; ++q) {
            const f32x4* p0 = (const f32x4*)(srcXf + (size_t)lrow * NW + kbase + q * 32);
            const f32x4* p1 = (const f32x4*)(srcXf + (size_t)(lrow + 16) * NW + kbase + q * 32);
            f32x4 x0a = p0[0], x0b = p0[1], x1a = p1[0], x1b = p1[1];
            short8 a0, a1;
#pragma unroll
            for (int j = 0; j < 4; ++j) {
              a0[j] = (short)f2bf(x0a[j]);
              a0[j + 4] = (short)f2bf(x0b[j]);
              a1[j] = (short)f2bf(x1a[j]);
              a1[j + 4] = (short)f2bf(x1b[j]);
            }
            r[q] = as_u4(a0);
            r[8 + q] = as_u4(a1);
          }
        }
      } else {
        poll_half(srcH + (size_t)lrow * NW + kbase, srcH + (size_t)(lrow + 16) * NW + kbase, r);
        u32x4 z4 = {0u, 0u, 0u, 0u};
        if (rm0) {
#pragma unroll
          for (int q = 0; q < 8; ++q) r[q] = z4;
        }
        if (rm1) {
#pragma unroll
          for (int q = 0; q < 8; ++q) r[8 + q] = z4;
        }
      }
#pragma unroll
      for (int q = 0; q < 8; ++q) {
        const int kt = half * 8 + q;
#pragma unroll
        for (int g = 0; g < 4; ++g) {
          acc[0][g] = __builtin_amdgcn_mfma_f32_16x16x32_bf16(as_s8(r[q]), wfrag[g][kt], acc[0][g], 0, 0, 0);
          acc[1][g] = __builtin_amdgcn_mfma_f32_16x16x32_bf16(as_s8(r[8 + q]), wfrag[g][kt], acc[1][g], 0, 0, 0);
        }
      }
    }

    // ---- cross-wave reduce via LDS ----
#pragma unroll
    for (int mt = 0; mt < 2; ++mt)
#pragma unroll
      for (int g = 0; g < 4; ++g)
#pragma unroll
        for (int r2 = 0; r2 < 4; ++r2)
          red[wave][mt][g][(lane >> 4) * 4 + r2][lrow] = acc[mt][g][r2];
    __syncthreads();

    // ---- epilogue: this thread's 2 cells (eb, n0) (eb, n0+1) ----
    {
      int rm = rmask[t * NB + eb];
      float hn[2];
#pragma unroll
      for (int j = 0; j < 2; ++j) {
        int n = n0 + j;
        float gv[4];
#pragma unroll
        for (int g = 0; g < 4; ++g)
          gv[g] = red[0][emt][g][er][n] + red[1][emt][g][er][n] +
                  red[2][emt][g][er][n] + red[3][emt][g][er][n] + bias_r[g][j];
        float c_old = creg[j];
        if (t == 0) {
          int cidx = (l * NB + eb) * NW + hb + n;
          c_old = BF16 ? bf2f(((const u16*)c0v)[cidx]) : ((const float*)c0v)[cidx];
        }
        if (rm) c_old = 0.f;
        float ci = sigmoidf_(gv[0]);
        float cf = sigmoidf_(gv[1]);
        float cg = tanhfast(gv[2]);
        float co = sigmoidf_(gv[3]);
        float cn = cf * c_old + ci * cg;
        hn[j] = co * tanhfast(cn);
        creg[j] = cn;
      }
      // publish h (write-through, packed 2x bf16) — consumers sentinel-poll this
      u32 hp = (u32)f2bf(hn[0]) | ((u32)f2bf(hn[1]) << 16);
      size_t hoff = ((size_t)l * 65 + (t + 1)) * (NB * NW) + (size_t)eb * NW + hb + n0;
      __hip_atomic_store((u32*)(hist + hoff), hp, __ATOMIC_RELAXED, __HIP_MEMORY_SCOPE_AGENT);
      // y output (layer 3)
      if (l == NLAY - 1) {
        size_t oy = ((size_t)t * NB + eb) * NW + hb + n0;
        if (BF16) ((u32*)outv)[oy >> 1] = hp;
        else { ((float*)outv)[oy] = hn[0]; ((float*)outv)[oy + 1] = hn[1]; }
      }
      // final c/h outputs
      if (t == NT - 1) {
        size_t oc = (size_t)NT * NB * NW + ((size_t)l * NB + eb) * NW + hb + n0;
        size_t oh = oc + (size_t)NLAY * NB * NW;
        if (BF16) {
          u32 cp = (u32)f2bf(creg[0]) | ((u32)f2bf(creg[1]) << 16);
          ((u32*)outv)[oc >> 1] = cp;
          ((u32*)outv)[oh >> 1] = hp;
        } else {
          ((float*)outv)[oc] = creg[0];
          ((float*)outv)[oc + 1] = creg[1];
          ((float*)outv)[oh] = hn[0];
          ((float*)outv)[oh + 1] = hn[1];
        }
      }
    }
    __syncthreads(); // protect red[] for next iteration
  }
}

// ---------------------------------------------------------------------------
extern "C" void kernel_launch(void* const* d_in, const int* in_sizes, int n_in,
                              void* d_out, int out_size, void* d_ws, size_t ws_size,
                              hipStream_t stream) {
  const void* x = d_in[0];
  const void* resets = d_in[1];
  const void* c0 = d_in[2];
  const void* h0 = d_in[3];
  const void* Wx = d_in[4];
  const void* Wh = d_in[5];
  const void* bias = d_in[6];

  char* ws = (char*)d_ws;
  u16* hist = (u16*)(ws + HIST_OFF);
  int* rmask = (int*)(ws + RMASK_OFF);
  int* modes = (int*)(ws + MODE_OFF);

  lstm_setup<<<1, 256, 0, stream>>>(x, resets, modes, rmask);
  lstm_poison<<<4096, 256, 0, stream>>>((u32*)hist);
  lstm_prep<true><<<512, 256, 0, stream>>>(h0, modes, hist);
  lstm_prep<false><<<512, 256, 0, stream>>>(h0, modes, hist);
  lstm_main<true><<<256, 256, 0, stream>>>(x, Wx, Wh, bias, c0, d_out, modes, rmask, hist);
  lstm_main<false><<<256, 256, 0, stream>>>(x, Wx, Wh, bias, c0, d_out, modes, rmask, hist);
}